// Round 20
// baseline (26121.527 us; speedup 1.0000x reference)
//
#include <hip/hip_runtime.h>

#define Bb 512
#define Tt 512
#define Ll 256
#define Ff 256
#define Hh 128
#define H3 384
#define NZ 8
#define XC 16
#define OC 8
#define CF 9
#define W3N 1152
#define BBt 2     // batches per CDE block -> 256 blocks

typedef float v2f __attribute__((ext_vector_type(2)));

__device__ __forceinline__ float sigm_fast(float x){ return 1.0f/(1.0f + __expf(-x)); }
__device__ __forceinline__ float softplus_fast(float x){
  float u = __expf(-fabsf(x));
  return fmaxf(x, 0.0f) + __logf(1.0f + u);
}
__device__ __forceinline__ float tanh_fast(float x){   // |err|~1e-7
  float xc = fminf(fmaxf(x, -9.f), 9.f);
  float e = __expf(2.f*xc);
  return (e - 1.f)/(e + 1.f);
}
// packed dual-FMA accumulate
__device__ __forceinline__ v2f pk4(float4 w, float4 z, v2f acc){
  v2f wl = {w.x, w.y}, wh = {w.z, w.w};
  v2f zl = {z.x, z.y}, zh = {z.z, z.w};
  acc += wl*zl;
  acc += wh*zh;
  return acc;
}
// involutive float4-index swizzle for [32]-float4 state rows
__device__ __forceinline__ int swz32(int i){ return i ^ ((i >> 3) & 3); }
__device__ __forceinline__ int swzf(int h){ return (((h >> 2) ^ ((h >> 5) & 3)) << 2) + (h & 3); }
// sum over lane bits 0..1: pure-DPP butterfly [HW-proven r15]
__device__ __forceinline__ float red4(float p){
  int t;
  t = __builtin_amdgcn_mov_dpp(__builtin_bit_cast(int, p), 0xB1, 0xF, 0xF, true); // xor1
  p += __builtin_bit_cast(float, t);
  t = __builtin_amdgcn_mov_dpp(__builtin_bit_cast(int, p), 0x4E, 0xF, 0xF, true); // xor2
  p += __builtin_bit_cast(float, t);
  return p;
}
// sum over lane bits 0..2: 2 DPP + 1 ds_swizzle [HW-proven r15]
__device__ __forceinline__ float red8(float p){
  p = red4(p);
  int t = __builtin_amdgcn_ds_swizzle(__builtin_bit_cast(int, p), 0x101F);        // xor4
  p += __builtin_bit_cast(float, t);
  return p;
}

// ---------------- GRU v5: fused zx(512) + zy(256) per block (r18, unchanged) --
__global__ __launch_bounds__(768) void gru_fused_kernel(
    const float* __restrict__ coeffs, const float* __restrict__ y_past,
    const float* __restrict__ tin,
    const float* __restrict__ zx_wih, const float* __restrict__ zx_whh,
    const float* __restrict__ zx_b,   const float* __restrict__ zx_bn,
    const float* __restrict__ zxlw,   const float* __restrict__ zxlb,
    const float* __restrict__ zy_wih, const float* __restrict__ zy_whh,
    const float* __restrict__ zy_b,   const float* __restrict__ zy_bn,
    float* __restrict__ out_zx, float* __restrict__ out_h)
{
  const int b = blockIdx.x;
  const int tid = threadIdx.x;
  const int j = tid >> 1;
  const int half = tid & 1;

  __shared__ __align__(16) float s_h[Hh];
  __shared__ float s_i[H3];
  __shared__ float s_g[H3];
  __shared__ float s_x[17];
  __shared__ float s_bn[Hh];
  __shared__ float s_zxlwT[NZ*Hh];
  __shared__ float s_zxlb[NZ];
  __shared__ float s_zxh[Ll][NZ];

  // ================= PHASE A: zx encoder, 512 steps =================
  {
    float wi[17];
    #pragma unroll
    for (int c = 0; c < 17; c++) wi[c] = zx_wih[j*17 + c];
    const float bj = zx_b[j];
    float4 wr[16];
    {
      const float4* p = reinterpret_cast<const float4*>(zx_whh + (size_t)j*Hh + half*64);
      #pragma unroll
      for (int q = 0; q < 16; q++) wr[q] = p[q];
    }

    if (tid < Hh){ s_h[tid] = 0.0f; s_bn[tid] = zx_bn[tid]; }
    for (int q2 = tid; q2 < NZ*Hh; q2 += 768){
      int o = q2 >> 7, rem = q2 & 127, m = rem >> 3, q = rem & 7;
      s_zxlwT[q*128 + o*16 + m] = zxlw[q2];
    }
    if (tid < NZ) s_zxlb[tid] = zxlb[tid];

    float xreg = 0.f;
    if (tid < 17)
      xreg = (tid < 16) ? coeffs[(size_t)b*Tt*XC + tid] : tin[0];
    __syncthreads();

    for (int t = 0; t < Tt; t++){
      if (tid < 17) s_x[tid] = xreg;
      __syncthreads();
      float ai = bj;
      #pragma unroll
      for (int c = 0; c < 17; c++) ai += wi[c]*s_x[c];
      float g0=0.f, g1=0.f, g2=0.f, g3=0.f;
      {
        const float4* h4p = reinterpret_cast<const float4*>(&s_h[half*64]);
        #pragma unroll
        for (int q = 0; q < 16; q++){
          float4 w = wr[q];
          float4 h4 = h4p[q];
          g0 += w.x*h4.x; g1 += w.y*h4.y; g2 += w.z*h4.z; g3 += w.w*h4.w;
        }
      }
      float g = (g0+g1)+(g2+g3);
      g += __shfl_xor(g, 1, 64);
      if (half == 0){ s_i[j] = ai; s_g[j] = g; }
      if (tid < 17 && t + 1 < Tt){
        const int tn = t + 1;
        xreg = (tid < 16) ? coeffs[(size_t)b*Tt*XC + (size_t)tn*XC + tid] : tin[tn];
      }
      __syncthreads();
      if (tid < Hh){
        float r  = sigm_fast(s_i[tid]       + s_g[tid]);
        float zz = sigm_fast(s_i[Hh + tid]  + s_g[Hh + tid]);
        float n  = tanh_fast(s_i[2*Hh+tid] + r*(s_g[2*Hh+tid] + s_bn[tid]));
        s_h[tid] = n + zz*(s_h[tid] - n);
      }
      __syncthreads();
      if (tid < Hh){
        int m = tid & 15;
        const float4* hp = reinterpret_cast<const float4*>(&s_h[m*8]);
        float4 ha = hp[0], hb = hp[1];
        float p = s_zxlwT[0*128 + tid]*ha.x + s_zxlwT[1*128 + tid]*ha.y
                + s_zxlwT[2*128 + tid]*ha.z + s_zxlwT[3*128 + tid]*ha.w
                + s_zxlwT[4*128 + tid]*hb.x + s_zxlwT[5*128 + tid]*hb.y
                + s_zxlwT[6*128 + tid]*hb.z + s_zxlwT[7*128 + tid]*hb.w;
        p += __shfl_xor(p, 1, 64); p += __shfl_xor(p, 2, 64);
        p += __shfl_xor(p, 4, 64); p += __shfl_xor(p, 8, 64);
        if (m == 0){
          int o = tid >> 4;
          float val = s_zxlb[o] + p;
          if (t < Ll) s_zxh[t][o] = val;
          else out_zx[(size_t)b*Tt*NZ + (size_t)t*NZ + o] = val;
        }
      }
    }
  }
  __syncthreads();

  // ================= PHASE B: zy encoder, 256 steps =================
  {
    float wi[17];
    #pragma unroll
    for (int c = 0; c < 17; c++) wi[c] = zy_wih[j*17 + c];
    const float bj = zy_b[j];
    float4 wr[16];
    {
      const float4* p = reinterpret_cast<const float4*>(zy_whh + (size_t)j*Hh + half*64);
      #pragma unroll
      for (int q = 0; q < 16; q++) wr[q] = p[q];
    }
    if (tid < Hh){ s_h[tid] = 0.0f; s_bn[tid] = zy_bn[tid]; }

    float xreg = 0.f;
    if (tid < 8)        xreg = y_past[(size_t)b*Ll*NZ + tid];
    else if (tid == 16) xreg = tin[0];
    __syncthreads();

    for (int t = 0; t < Ll; t++){
      if (tid < 8)        s_x[tid] = xreg;
      else if (tid < 16)  s_x[tid] = s_zxh[t][tid - 8];
      else if (tid == 16) s_x[16] = xreg;
      __syncthreads();
      float ai = bj;
      #pragma unroll
      for (int c = 0; c < 17; c++) ai += wi[c]*s_x[c];
      float g0=0.f, g1=0.f, g2=0.f, g3=0.f;
      {
        const float4* h4p = reinterpret_cast<const float4*>(&s_h[half*64]);
        #pragma unroll
        for (int q = 0; q < 16; q++){
          float4 w = wr[q];
          float4 h4 = h4p[q];
          g0 += w.x*h4.x; g1 += w.y*h4.y; g2 += w.z*h4.z; g3 += w.w*h4.w;
        }
      }
      float g = (g0+g1)+(g2+g3);
      g += __shfl_xor(g, 1, 64);
      if (half == 0){ s_i[j] = ai; s_g[j] = g; }
      if (t + 1 < Ll){
        if (tid < 8)        xreg = y_past[(size_t)b*Ll*NZ + (size_t)(t+1)*NZ + tid];
        else if (tid == 16) xreg = tin[t+1];
      }
      __syncthreads();
      if (tid < Hh){
        float r  = sigm_fast(s_i[tid]       + s_g[tid]);
        float zz = sigm_fast(s_i[Hh + tid]  + s_g[Hh + tid]);
        float n  = tanh_fast(s_i[2*Hh+tid] + r*(s_g[2*Hh+tid] + s_bn[tid]));
        s_h[tid] = n + zz*(s_h[tid] - n);
      }
      __syncthreads();
    }
    if (tid < Hh) out_h[b*Hh + tid] = s_h[tid];
  }
}

// ---------------- CDE RK4 v15 — w1/w2 streamed, LDS ~21KB -> 2 blocks/CU ------
// 256 blocks x 2 batches x 512 threads; waves_per_eu(4,4) budgets 128 VGPR and
// enables 2 co-resident blocks (4 waves/SIMD) for latency hiding.
__global__ __launch_bounds__(512)
__attribute__((amdgpu_waves_per_eu(4, 4)))
void cde_fp32_kernel(
    const float* __restrict__ zy_h, const float* __restrict__ zx,
    const float* __restrict__ tin,
    const float* __restrict__ fw1, const float* __restrict__ fb1,
    const float* __restrict__ fw2, const float* __restrict__ fb2,
    const float* __restrict__ fw3, const float* __restrict__ fb3,
    const float* __restrict__ rw,  const float* __restrict__ rb,
    float* __restrict__ yout)
{
  const int tid = threadIdx.x;
  const int c12 = tid >> 2;      // G1/G2: output col 0..127
  const int q4  = tid & 3;       // G1/G2: k-quarter
  const int col64 = tid >> 3;    // G3: col-in-group 0..63
  const int e8    = tid & 7;     // G3: k-eighth (16 floats)
  const int bg = blockIdx.x * BBt;

  __shared__ __align__(16) float4 s_zinv[BBt][32];  // swizzled state rows
  __shared__ __align__(16) float4 s_h1v[BBt][32];
  __shared__ __align__(16) float4 s_h2v[BBt][32];
  __shared__ float s_o[BBt][W3N];                // raw pre-activations (9.2KB)
  __shared__ float s_z[BBt][Hh];
  __shared__ float s_kacc[BBt][Hh];
  __shared__ float s_dx[BBt][CF];
  __shared__ float s_rw[OC*Hh];
  __shared__ float s_rb[OC];
  __shared__ float s_b3[W3N];

  float* zin_f0 = reinterpret_cast<float*>(&s_zinv[0][0]);
  float* zin_f1 = reinterpret_cast<float*>(&s_zinv[1][0]);
  float* h1_f0  = reinterpret_cast<float*>(&s_h1v[0][0]);
  float* h1_f1  = reinterpret_cast<float*>(&s_h1v[1][0]);
  float* h2_f0  = reinterpret_cast<float*>(&s_h2v[0][0]);
  float* h2_f1  = reinterpret_cast<float*>(&s_h2v[1][0]);

  const float b1r = fb1[c12], b2r = fb2[c12];
  for (int idx = tid; idx < W3N; idx += 512) s_b3[idx] = fb3[idx];
  for (int idx = tid; idx < OC*Hh; idx += 512) s_rw[idx] = rw[idx];
  if (tid < OC) s_rb[tid] = rb[tid];
  if (tid < BBt*Hh){
    int b = tid >> 7, h = tid & 127;
    float zv = zy_h[(size_t)(bg + b)*Hh + h];
    s_z[b][h] = zv;
    (b == 0 ? zin_f0 : zin_f1)[swzf(h)] = zv;
  }
  __syncthreads();

  // y[:, 0, :]
  if (tid < 256){
    int b = tid >> 7, r = tid & 127, o = r >> 4, seg = r & 15;
    float p = 0.f;
    #pragma unroll
    for (int q = 0; q < 8; q++)
      p += s_z[b][seg*8 + q]*s_rw[o*Hh + seg*8 + q];
    p += __shfl_xor(p, 1, 64); p += __shfl_xor(p, 2, 64);
    p += __shfl_xor(p, 4, 64); p += __shfl_xor(p, 8, 64);
    if (seg == 0) yout[(size_t)(bg + b)*Ff*OC + o] = s_rb[o] + p;
  }

  const float* w1p = fw1 + (size_t)c12*Hh + q4*32;     // G1 weights (L2-hot)
  const float* w2p = fw2 + (size_t)c12*Hh + q4*32;     // G2 weights
  const float* w3p = fw3 + (size_t)col64*Hh + e8*16;   // + g*8192 floats per iter

  for (int i = 0; i < Ff - 1; i++){
    for (int st = 0; st < 4; st++){
      // ---- issue w3 iters 0,1 now; latency hides under G1/G2 ----
      float4 A0, A1, A2, A3, B0, B1, B2, B3;
      {
        const float4* pA = reinterpret_cast<const float4*>(w3p);
        const float4* pB = reinterpret_cast<const float4*>(w3p + 8192);
        A0 = pA[0]; A1 = pA[1]; A2 = pA[2]; A3 = pA[3];
        B0 = pB[0]; B1 = pB[1]; B2 = pB[2]; B3 = pB[3];
      }
      // ---- dX fold (st==0 only) ----
      if (st == 0 && tid < BBt*CF){
        int b = tid/CF, c = tid%CF;
        float d;
        if (c < 8){
          const float* zp = zx + (size_t)(bg + b)*Tt*NZ + (size_t)(Ll + i)*NZ + c;
          d = zp[NZ] - zp[0];
        } else {
          d = tin[Ll + i + 1] - tin[Ll + i];
        }
        s_dx[b][c] = d;
      }
      // ---- G1: weights streamed from L2; packed FMA + DPP reduce ----
      {
        float4 wv[8];
        {
          const float4* p1 = reinterpret_cast<const float4*>(w1p);
          #pragma unroll
          for (int j = 0; j < 8; j++) wv[j] = p1[j];
        }
        v2f a0 = {0.f, 0.f}, a1 = {0.f, 0.f};
        #pragma unroll
        for (int jj = 0; jj < 8; jj++){
          float4 z0 = s_zinv[0][swz32(q4*8 + jj)];
          float4 z1 = s_zinv[1][swz32(q4*8 + jj)];
          a0 = pk4(wv[jj], z0, a0); a1 = pk4(wv[jj], z1, a1);
        }
        float p0 = red4(a0.x + a0.y), p1 = red4(a1.x + a1.y);
        if (q4 == 0){
          h1_f0[swzf(c12)] = softplus_fast(b1r + p0);
          h1_f1[swzf(c12)] = softplus_fast(b1r + p1);
        }
      }
      __syncthreads();
      // ---- G2 ----
      {
        float4 wv[8];
        {
          const float4* p2 = reinterpret_cast<const float4*>(w2p);
          #pragma unroll
          for (int j = 0; j < 8; j++) wv[j] = p2[j];
        }
        v2f a0 = {0.f, 0.f}, a1 = {0.f, 0.f};
        #pragma unroll
        for (int jj = 0; jj < 8; jj++){
          float4 z0 = s_h1v[0][swz32(q4*8 + jj)];
          float4 z1 = s_h1v[1][swz32(q4*8 + jj)];
          a0 = pk4(wv[jj], z0, a0); a1 = pk4(wv[jj], z1, a1);
        }
        float p0 = red4(a0.x + a0.y), p1 = red4(a1.x + a1.y);
        if (q4 == 0){
          h2_f0[swzf(c12)] = softplus_fast(b2r + p0);
          h2_f1[swzf(c12)] = softplus_fast(b2r + p1);
        }
      }
      __syncthreads();
      // ---- G3: 18 iters, 2-deep A/B pipeline, packed FMA, red8 ----
      {
        float4 h2a0 = s_h2v[0][swz32(e8*4 + 0)];
        float4 h2a1 = s_h2v[0][swz32(e8*4 + 1)];
        float4 h2a2 = s_h2v[0][swz32(e8*4 + 2)];
        float4 h2a3 = s_h2v[0][swz32(e8*4 + 3)];
        float4 h2b0 = s_h2v[1][swz32(e8*4 + 0)];
        float4 h2b1 = s_h2v[1][swz32(e8*4 + 1)];
        float4 h2b2 = s_h2v[1][swz32(e8*4 + 2)];
        float4 h2b3 = s_h2v[1][swz32(e8*4 + 3)];
        #pragma unroll 2
        for (int g = 0; g < 18; g++){
          float4 c0, c1, c2, c3;
          if ((g & 1) == 0){
            c0 = A0; c1 = A1; c2 = A2; c3 = A3;
            if (g + 2 < 18){
              const float4* pF = reinterpret_cast<const float4*>(w3p + (size_t)(g+2)*8192);
              A0 = pF[0]; A1 = pF[1]; A2 = pF[2]; A3 = pF[3];
            }
          } else {
            c0 = B0; c1 = B1; c2 = B2; c3 = B3;
            if (g + 2 < 18){
              const float4* pF = reinterpret_cast<const float4*>(w3p + (size_t)(g+2)*8192);
              B0 = pF[0]; B1 = pF[1]; B2 = pF[2]; B3 = pF[3];
            }
          }
          v2f a0 = {0.f, 0.f}, a1 = {0.f, 0.f};
          a0 = pk4(c0, h2a0, a0); a0 = pk4(c1, h2a1, a0);
          a0 = pk4(c2, h2a2, a0); a0 = pk4(c3, h2a3, a0);
          a1 = pk4(c0, h2b0, a1); a1 = pk4(c1, h2b1, a1);
          a1 = pk4(c2, h2b2, a1); a1 = pk4(c3, h2b3, a1);
          float p0 = red8(a0.x + a0.y), p1 = red8(a1.x + a1.y);
          if (e8 == 0){
            int n = g*64 + col64;
            s_o[0][n] = s_b3[n] + p0;
            s_o[1][n] = s_b3[n] + p1;
          }
        }
      }
      __syncthreads();
      // ---- phase B: 512 threads = 256 pairs x 2 halves; shfl(1) combine ----
      {
        int pr = tid >> 1, hf = tid & 1;
        int b = pr >> 7, h = pr & 127;
        const float* ob = &s_o[0][0] + b*W3N + h*CF;
        float kc = 0.f;
        #pragma unroll
        for (int jj = 0; jj < 4; jj++){
          int c = hf*4 + jj;
          kc += tanh_fast(ob[c]) * s_dx[b][c];
        }
        if (hf) kc += tanh_fast(ob[8]) * s_dx[b][8];
        kc += __shfl_xor(kc, 1, 64);
        if (hf == 0){
          float zv = s_z[b][h], zin;
          if      (st == 0){ s_kacc[b][h] = kc;        zin = zv + 0.5f*kc; }
          else if (st == 1){ s_kacc[b][h] += 2.f*kc;   zin = zv + 0.5f*kc; }
          else if (st == 2){ s_kacc[b][h] += 2.f*kc;   zin = zv + kc; }
          else { float zn = zv + (s_kacc[b][h] + kc)*(1.f/6.f); s_z[b][h] = zn; zin = zn; }
          (b == 0 ? zin_f0 : zin_f1)[swzf(h)] = zin;
        }
      }
      __syncthreads();
    }
    // readout y[:, i+1, :]
    if (tid < 256){
      int b = tid >> 7, r = tid & 127, o = r >> 4, seg = r & 15;
      float p = 0.f;
      #pragma unroll
      for (int q = 0; q < 8; q++)
        p += s_z[b][seg*8 + q]*s_rw[o*Hh + seg*8 + q];
      p += __shfl_xor(p, 1, 64); p += __shfl_xor(p, 2, 64);
      p += __shfl_xor(p, 4, 64); p += __shfl_xor(p, 8, 64);
      if (seg == 0) yout[(size_t)(bg + b)*Ff*OC + (size_t)(i + 1)*OC + o] = s_rb[o] + p;
    }
  }
}

extern "C" void kernel_launch(void* const* d_in, const int* in_sizes, int n_in,
                              void* d_out, int out_size, void* d_ws, size_t ws_size,
                              hipStream_t stream)
{
  (void)in_sizes; (void)n_in; (void)out_size; (void)ws_size;
  const float* y_past = (const float*)d_in[0];
  const float* t_in   = (const float*)d_in[1];
  const float* coeffs = (const float*)d_in[2];
  // d_in[3] = input_length (fixed 256)
  const float* zx_wih = (const float*)d_in[4];
  const float* zx_whh = (const float*)d_in[5];
  const float* zx_b   = (const float*)d_in[6];
  const float* zx_bn  = (const float*)d_in[7];
  const float* zxl_w  = (const float*)d_in[8];
  const float* zxl_b  = (const float*)d_in[9];
  const float* zy_wih = (const float*)d_in[10];
  const float* zy_whh = (const float*)d_in[11];
  const float* zy_b   = (const float*)d_in[12];
  const float* zy_bn  = (const float*)d_in[13];
  const float* fw1 = (const float*)d_in[14];
  const float* fb1 = (const float*)d_in[15];
  const float* fw2 = (const float*)d_in[16];
  const float* fb2 = (const float*)d_in[17];
  const float* fw3 = (const float*)d_in[18];
  const float* fb3 = (const float*)d_in[19];
  const float* r_w = (const float*)d_in[20];
  const float* r_b = (const float*)d_in[21];

  float* ws = (float*)d_ws;
  float* zx_buf = ws;                              // B*T*NZ fp32 = 8.39 MB
  float* zy_buf = ws + (size_t)Bb*Tt*NZ;           // B*H fp32   = 256 KB

  gru_fused_kernel<<<Bb, 768, 0, stream>>>(coeffs, y_past, t_in,
                                           zx_wih, zx_whh, zx_b, zx_bn,
                                           zxl_w, zxl_b,
                                           zy_wih, zy_whh, zy_b, zy_bn,
                                           zx_buf, zy_buf);
  cde_fp32_kernel<<<Bb/BBt, 512, 0, stream>>>(zy_buf, zx_buf, t_in,
                                              fw1, fb1, fw2, fb2, fw3, fb3,
                                              r_w, r_b, (float*)d_out);
}

// Round 21
// 11879.697 us; speedup vs baseline: 2.1988x; 2.1988x over previous
//
#include <hip/hip_runtime.h>

#define Bb 512
#define Tt 512
#define Ll 256
#define Ff 256
#define Hh 128
#define H3 384
#define NZ 8
#define XC 16
#define OC 8
#define CF 9
#define W3N 1152
#define BBt 2     // batches per CDE block -> 256 blocks (1/CU)

typedef float v2f __attribute__((ext_vector_type(2)));

__device__ __forceinline__ float sigm_fast(float x){ return 1.0f/(1.0f + __expf(-x)); }
__device__ __forceinline__ float softplus_fast(float x){
  float u = __expf(-fabsf(x));
  return fmaxf(x, 0.0f) + __logf(1.0f + u);
}
__device__ __forceinline__ float tanh_fast(float x){   // |err|~1e-7
  float xc = fminf(fmaxf(x, -9.f), 9.f);
  float e = __expf(2.f*xc);
  return (e - 1.f)/(e + 1.f);
}
// packed dual-FMA accumulate: acc += {w.x*z.x, w.y*z.y} twice per float4
__device__ __forceinline__ v2f pk4(float4 w, float4 z, v2f acc){
  v2f wl = {w.x, w.y}, wh = {w.z, w.w};
  v2f zl = {z.x, z.y}, zh = {z.z, z.w};
  acc += wl*zl;       // -> v_pk_fma_f32
  acc += wh*zh;
  return acc;
}
// involutive float4-index swizzle for [32]-float4 state rows
__device__ __forceinline__ int swz32(int i){ return i ^ ((i >> 3) & 3); }
__device__ __forceinline__ int swzf(int h){ return (((h >> 2) ^ ((h >> 5) & 3)) << 2) + (h & 3); }
// sum over lane bits 0..1: pure-DPP butterfly (no DS) [HW-proven r15]
__device__ __forceinline__ float red4(float p){
  int t;
  t = __builtin_amdgcn_mov_dpp(__builtin_bit_cast(int, p), 0xB1, 0xF, 0xF, true); // xor1
  p += __builtin_bit_cast(float, t);
  t = __builtin_amdgcn_mov_dpp(__builtin_bit_cast(int, p), 0x4E, 0xF, 0xF, true); // xor2
  p += __builtin_bit_cast(float, t);
  return p;
}
// sum over lane bits 0..2: 2 DPP + 1 ds_swizzle [HW-proven r15]
__device__ __forceinline__ float red8(float p){
  p = red4(p);
  int t = __builtin_amdgcn_ds_swizzle(__builtin_bit_cast(int, p), 0x101F);        // xor4
  p += __builtin_bit_cast(float, t);
  return p;
}

// ---------------- GRU v5: fused zx(512) + zy(256) per block (r18, unchanged) --
__global__ __launch_bounds__(768) void gru_fused_kernel(
    const float* __restrict__ coeffs, const float* __restrict__ y_past,
    const float* __restrict__ tin,
    const float* __restrict__ zx_wih, const float* __restrict__ zx_whh,
    const float* __restrict__ zx_b,   const float* __restrict__ zx_bn,
    const float* __restrict__ zxlw,   const float* __restrict__ zxlb,
    const float* __restrict__ zy_wih, const float* __restrict__ zy_whh,
    const float* __restrict__ zy_b,   const float* __restrict__ zy_bn,
    float* __restrict__ out_zx, float* __restrict__ out_h)
{
  const int b = blockIdx.x;
  const int tid = threadIdx.x;
  const int j = tid >> 1;
  const int half = tid & 1;

  __shared__ __align__(16) float s_h[Hh];
  __shared__ float s_i[H3];
  __shared__ float s_g[H3];
  __shared__ float s_x[17];
  __shared__ float s_bn[Hh];
  __shared__ float s_zxlwT[NZ*Hh];
  __shared__ float s_zxlb[NZ];
  __shared__ float s_zxh[Ll][NZ];

  // ================= PHASE A: zx encoder, 512 steps =================
  {
    float wi[17];
    #pragma unroll
    for (int c = 0; c < 17; c++) wi[c] = zx_wih[j*17 + c];
    const float bj = zx_b[j];
    float4 wr[16];
    {
      const float4* p = reinterpret_cast<const float4*>(zx_whh + (size_t)j*Hh + half*64);
      #pragma unroll
      for (int q = 0; q < 16; q++) wr[q] = p[q];
    }

    if (tid < Hh){ s_h[tid] = 0.0f; s_bn[tid] = zx_bn[tid]; }
    for (int q2 = tid; q2 < NZ*Hh; q2 += 768){
      int o = q2 >> 7, rem = q2 & 127, m = rem >> 3, q = rem & 7;
      s_zxlwT[q*128 + o*16 + m] = zxlw[q2];
    }
    if (tid < NZ) s_zxlb[tid] = zxlb[tid];

    float xreg = 0.f;
    if (tid < 17)
      xreg = (tid < 16) ? coeffs[(size_t)b*Tt*XC + tid] : tin[0];
    __syncthreads();

    for (int t = 0; t < Tt; t++){
      if (tid < 17) s_x[tid] = xreg;
      __syncthreads();
      float ai = bj;
      #pragma unroll
      for (int c = 0; c < 17; c++) ai += wi[c]*s_x[c];
      float g0=0.f, g1=0.f, g2=0.f, g3=0.f;
      {
        const float4* h4p = reinterpret_cast<const float4*>(&s_h[half*64]);
        #pragma unroll
        for (int q = 0; q < 16; q++){
          float4 w = wr[q];
          float4 h4 = h4p[q];
          g0 += w.x*h4.x; g1 += w.y*h4.y; g2 += w.z*h4.z; g3 += w.w*h4.w;
        }
      }
      float g = (g0+g1)+(g2+g3);
      g += __shfl_xor(g, 1, 64);
      if (half == 0){ s_i[j] = ai; s_g[j] = g; }
      if (tid < 17 && t + 1 < Tt){
        const int tn = t + 1;
        xreg = (tid < 16) ? coeffs[(size_t)b*Tt*XC + (size_t)tn*XC + tid] : tin[tn];
      }
      __syncthreads();
      if (tid < Hh){
        float r  = sigm_fast(s_i[tid]       + s_g[tid]);
        float zz = sigm_fast(s_i[Hh + tid]  + s_g[Hh + tid]);
        float n  = tanh_fast(s_i[2*Hh+tid] + r*(s_g[2*Hh+tid] + s_bn[tid]));
        s_h[tid] = n + zz*(s_h[tid] - n);
      }
      __syncthreads();
      if (tid < Hh){
        int m = tid & 15;
        const float4* hp = reinterpret_cast<const float4*>(&s_h[m*8]);
        float4 ha = hp[0], hb = hp[1];
        float p = s_zxlwT[0*128 + tid]*ha.x + s_zxlwT[1*128 + tid]*ha.y
                + s_zxlwT[2*128 + tid]*ha.z + s_zxlwT[3*128 + tid]*ha.w
                + s_zxlwT[4*128 + tid]*hb.x + s_zxlwT[5*128 + tid]*hb.y
                + s_zxlwT[6*128 + tid]*hb.z + s_zxlwT[7*128 + tid]*hb.w;
        p += __shfl_xor(p, 1, 64); p += __shfl_xor(p, 2, 64);
        p += __shfl_xor(p, 4, 64); p += __shfl_xor(p, 8, 64);
        if (m == 0){
          int o = tid >> 4;
          float val = s_zxlb[o] + p;
          if (t < Ll) s_zxh[t][o] = val;
          else out_zx[(size_t)b*Tt*NZ + (size_t)t*NZ + o] = val;
        }
      }
    }
  }
  __syncthreads();

  // ================= PHASE B: zy encoder, 256 steps =================
  {
    float wi[17];
    #pragma unroll
    for (int c = 0; c < 17; c++) wi[c] = zy_wih[j*17 + c];
    const float bj = zy_b[j];
    float4 wr[16];
    {
      const float4* p = reinterpret_cast<const float4*>(zy_whh + (size_t)j*Hh + half*64);
      #pragma unroll
      for (int q = 0; q < 16; q++) wr[q] = p[q];
    }
    if (tid < Hh){ s_h[tid] = 0.0f; s_bn[tid] = zy_bn[tid]; }

    float xreg = 0.f;
    if (tid < 8)        xreg = y_past[(size_t)b*Ll*NZ + tid];
    else if (tid == 16) xreg = tin[0];
    __syncthreads();

    for (int t = 0; t < Ll; t++){
      if (tid < 8)        s_x[tid] = xreg;
      else if (tid < 16)  s_x[tid] = s_zxh[t][tid - 8];
      else if (tid == 16) s_x[16] = xreg;
      __syncthreads();
      float ai = bj;
      #pragma unroll
      for (int c = 0; c < 17; c++) ai += wi[c]*s_x[c];
      float g0=0.f, g1=0.f, g2=0.f, g3=0.f;
      {
        const float4* h4p = reinterpret_cast<const float4*>(&s_h[half*64]);
        #pragma unroll
        for (int q = 0; q < 16; q++){
          float4 w = wr[q];
          float4 h4 = h4p[q];
          g0 += w.x*h4.x; g1 += w.y*h4.y; g2 += w.z*h4.z; g3 += w.w*h4.w;
        }
      }
      float g = (g0+g1)+(g2+g3);
      g += __shfl_xor(g, 1, 64);
      if (half == 0){ s_i[j] = ai; s_g[j] = g; }
      if (t + 1 < Ll){
        if (tid < 8)        xreg = y_past[(size_t)b*Ll*NZ + (size_t)(t+1)*NZ + tid];
        else if (tid == 16) xreg = tin[t+1];
      }
      __syncthreads();
      if (tid < Hh){
        float r  = sigm_fast(s_i[tid]       + s_g[tid]);
        float zz = sigm_fast(s_i[Hh + tid]  + s_g[Hh + tid]);
        float n  = tanh_fast(s_i[2*Hh+tid] + r*(s_g[2*Hh+tid] + s_bn[tid]));
        s_h[tid] = n + zz*(s_h[tid] - n);
      }
      __syncthreads();
    }
    if (tid < Hh) out_h[b*Hh + tid] = s_h[tid];
  }
}

// ---------------- CDE RK4 v14 — r19 proven config (92 VGPR, no spill) ---------
// 256 blocks (1/CU) x 2 batches x 512 threads; waves_per_eu(2,2) is the ONLY
// allocator-safe setting (r12/r14/r15/r20 evidence).
__global__ __launch_bounds__(512)
__attribute__((amdgpu_waves_per_eu(2, 2)))
void cde_fp32_kernel(
    const float* __restrict__ zy_h, const float* __restrict__ zx,
    const float* __restrict__ tin,
    const float* __restrict__ fw1, const float* __restrict__ fb1,
    const float* __restrict__ fw2, const float* __restrict__ fb2,
    const float* __restrict__ fw3, const float* __restrict__ fb3,
    const float* __restrict__ rw,  const float* __restrict__ rb,
    float* __restrict__ yout)
{
  const int tid = threadIdx.x;
  const int c12 = tid >> 2;      // G1/G2: output col 0..127
  const int q4  = tid & 3;       // G1/G2: k-quarter
  const int col64 = tid >> 3;    // G3: col-in-group 0..63
  const int e8    = tid & 7;     // G3: k-eighth (16 floats)
  const int bg = blockIdx.x * BBt;

  __shared__ __align__(16) float4 s_w1v[4096];   // 64 KB, [jj][col*4+q4]
  __shared__ __align__(16) float4 s_w2v[4096];   // 64 KB
  __shared__ __align__(16) float4 s_zinv[BBt][32];  // swizzled state rows
  __shared__ __align__(16) float4 s_h1v[BBt][32];
  __shared__ __align__(16) float4 s_h2v[BBt][32];
  __shared__ float s_o[BBt][W3N];                // raw pre-activations
  __shared__ float s_z[BBt][Hh];
  __shared__ float s_kacc[BBt][Hh];
  __shared__ float s_dx[BBt][CF];
  __shared__ float s_rw[OC*Hh];
  __shared__ float s_rb[OC];
  __shared__ float s_b3[W3N];

  float* zin_f0 = reinterpret_cast<float*>(&s_zinv[0][0]);
  float* zin_f1 = reinterpret_cast<float*>(&s_zinv[1][0]);
  float* h1_f0  = reinterpret_cast<float*>(&s_h1v[0][0]);
  float* h1_f1  = reinterpret_cast<float*>(&s_h1v[1][0]);
  float* h2_f0  = reinterpret_cast<float*>(&s_h2v[0][0]);
  float* h2_f1  = reinterpret_cast<float*>(&s_h2v[1][0]);

  // ---- one-time: w1/w2 -> [jj][col*4+q] layout; biases, readout, init ----
  for (int idx = tid; idx < Hh*32; idx += 512){
    int col = idx >> 5, jcol = idx & 31;
    int q = jcol >> 3, jj = jcol & 7;
    int dst = jj*512 + col*4 + q;
    s_w1v[dst] = reinterpret_cast<const float4*>(fw1)[idx];
    s_w2v[dst] = reinterpret_cast<const float4*>(fw2)[idx];
  }
  const float b1r = fb1[c12], b2r = fb2[c12];
  for (int idx = tid; idx < W3N; idx += 512) s_b3[idx] = fb3[idx];
  for (int idx = tid; idx < OC*Hh; idx += 512) s_rw[idx] = rw[idx];
  if (tid < OC) s_rb[tid] = rb[tid];
  if (tid < BBt*Hh){
    int b = tid >> 7, h = tid & 127;
    float zv = zy_h[(size_t)(bg + b)*Hh + h];
    s_z[b][h] = zv;
    (b == 0 ? zin_f0 : zin_f1)[swzf(h)] = zv;
  }
  __syncthreads();

  // y[:, 0, :]
  if (tid < 256){
    int b = tid >> 7, r = tid & 127, o = r >> 4, seg = r & 15;
    float p = 0.f;
    #pragma unroll
    for (int q = 0; q < 8; q++)
      p += s_z[b][seg*8 + q]*s_rw[o*Hh + seg*8 + q];
    p += __shfl_xor(p, 1, 64); p += __shfl_xor(p, 2, 64);
    p += __shfl_xor(p, 4, 64); p += __shfl_xor(p, 8, 64);
    if (seg == 0) yout[(size_t)(bg + b)*Ff*OC + o] = s_rb[o] + p;
  }

  const float* w3p = fw3 + (size_t)col64*Hh + e8*16;   // + g*8192 floats per iter

  for (int i = 0; i < Ff - 1; i++){
    for (int st = 0; st < 4; st++){
      // ---- issue w3 iters 0,1 now; latency hides under G1/G2 (2-deep only!) ----
      float4 A0, A1, A2, A3, B0, B1, B2, B3;
      {
        const float4* pA = reinterpret_cast<const float4*>(w3p);
        const float4* pB = reinterpret_cast<const float4*>(w3p + 8192);
        A0 = pA[0]; A1 = pA[1]; A2 = pA[2]; A3 = pA[3];
        B0 = pB[0]; B1 = pB[1]; B2 = pB[2]; B3 = pB[3];
      }
      // ---- dX fold (st==0 only): prev consumer was phase B of i-1, >=1 barrier ago
      if (st == 0 && tid < BBt*CF){
        int b = tid/CF, c = tid%CF;
        float d;
        if (c < 8){
          const float* zp = zx + (size_t)(bg + b)*Tt*NZ + (size_t)(Ll + i)*NZ + c;
          d = zp[NZ] - zp[0];
        } else {
          d = tin[Ll + i + 1] - tin[Ll + i];
        }
        s_dx[b][c] = d;
      }
      // ---- G1: h1 = softplus(zin @ w1.T + b1); packed FMA + DPP reduce ----
      {
        v2f a0 = {0.f, 0.f}, a1 = {0.f, 0.f};
        #pragma unroll
        for (int jj = 0; jj < 8; jj++){
          float4 z0 = s_zinv[0][swz32(q4*8 + jj)];
          float4 z1 = s_zinv[1][swz32(q4*8 + jj)];
          float4 w = s_w1v[jj*512 + tid];
          a0 = pk4(w, z0, a0); a1 = pk4(w, z1, a1);
        }
        float p0 = red4(a0.x + a0.y), p1 = red4(a1.x + a1.y);
        if (q4 == 0){
          h1_f0[swzf(c12)] = softplus_fast(b1r + p0);
          h1_f1[swzf(c12)] = softplus_fast(b1r + p1);
        }
      }
      __syncthreads();
      // ---- G2 ----
      {
        v2f a0 = {0.f, 0.f}, a1 = {0.f, 0.f};
        #pragma unroll
        for (int jj = 0; jj < 8; jj++){
          float4 z0 = s_h1v[0][swz32(q4*8 + jj)];
          float4 z1 = s_h1v[1][swz32(q4*8 + jj)];
          float4 w = s_w2v[jj*512 + tid];
          a0 = pk4(w, z0, a0); a1 = pk4(w, z1, a1);
        }
        float p0 = red4(a0.x + a0.y), p1 = red4(a1.x + a1.y);
        if (q4 == 0){
          h2_f0[swzf(c12)] = softplus_fast(b2r + p0);
          h2_f1[swzf(c12)] = softplus_fast(b2r + p1);
        }
      }
      __syncthreads();
      // ---- G3: 18 iters, 2-deep A/B pipeline, packed FMA, red8 ----
      {
        float4 h2a0 = s_h2v[0][swz32(e8*4 + 0)];
        float4 h2a1 = s_h2v[0][swz32(e8*4 + 1)];
        float4 h2a2 = s_h2v[0][swz32(e8*4 + 2)];
        float4 h2a3 = s_h2v[0][swz32(e8*4 + 3)];
        float4 h2b0 = s_h2v[1][swz32(e8*4 + 0)];
        float4 h2b1 = s_h2v[1][swz32(e8*4 + 1)];
        float4 h2b2 = s_h2v[1][swz32(e8*4 + 2)];
        float4 h2b3 = s_h2v[1][swz32(e8*4 + 3)];
        #pragma unroll 2
        for (int g = 0; g < 18; g++){
          float4 c0, c1, c2, c3;
          if ((g & 1) == 0){
            c0 = A0; c1 = A1; c2 = A2; c3 = A3;
            if (g + 2 < 18){
              const float4* pF = reinterpret_cast<const float4*>(w3p + (size_t)(g+2)*8192);
              A0 = pF[0]; A1 = pF[1]; A2 = pF[2]; A3 = pF[3];
            }
          } else {
            c0 = B0; c1 = B1; c2 = B2; c3 = B3;
            if (g + 2 < 18){
              const float4* pF = reinterpret_cast<const float4*>(w3p + (size_t)(g+2)*8192);
              B0 = pF[0]; B1 = pF[1]; B2 = pF[2]; B3 = pF[3];
            }
          }
          v2f a0 = {0.f, 0.f}, a1 = {0.f, 0.f};
          a0 = pk4(c0, h2a0, a0); a0 = pk4(c1, h2a1, a0);
          a0 = pk4(c2, h2a2, a0); a0 = pk4(c3, h2a3, a0);
          a1 = pk4(c0, h2b0, a1); a1 = pk4(c1, h2b1, a1);
          a1 = pk4(c2, h2b2, a1); a1 = pk4(c3, h2b3, a1);
          float p0 = red8(a0.x + a0.y), p1 = red8(a1.x + a1.y);
          if (e8 == 0){
            int n = g*64 + col64;
            s_o[0][n] = s_b3[n] + p0;
            s_o[1][n] = s_b3[n] + p1;
          }
        }
      }
      __syncthreads();
      // ---- phase B: 512 threads = 256 pairs x 2 halves; shfl(1) combine ----
      {
        int pr = tid >> 1, hf = tid & 1;
        int b = pr >> 7, h = pr & 127;
        const float* ob = &s_o[0][0] + b*W3N + h*CF;
        float kc = 0.f;
        #pragma unroll
        for (int jj = 0; jj < 4; jj++){
          int c = hf*4 + jj;
          kc += tanh_fast(ob[c]) * s_dx[b][c];
        }
        if (hf) kc += tanh_fast(ob[8]) * s_dx[b][8];
        kc += __shfl_xor(kc, 1, 64);
        if (hf == 0){
          float zv = s_z[b][h], zin;
          if      (st == 0){ s_kacc[b][h] = kc;        zin = zv + 0.5f*kc; }
          else if (st == 1){ s_kacc[b][h] += 2.f*kc;   zin = zv + 0.5f*kc; }
          else if (st == 2){ s_kacc[b][h] += 2.f*kc;   zin = zv + kc; }
          else { float zn = zv + (s_kacc[b][h] + kc)*(1.f/6.f); s_z[b][h] = zn; zin = zn; }
          (b == 0 ? zin_f0 : zin_f1)[swzf(h)] = zin;
        }
      }
      __syncthreads();
    }
    // readout y[:, i+1, :]
    if (tid < 256){
      int b = tid >> 7, r = tid & 127, o = r >> 4, seg = r & 15;
      float p = 0.f;
      #pragma unroll
      for (int q = 0; q < 8; q++)
        p += s_z[b][seg*8 + q]*s_rw[o*Hh + seg*8 + q];
      p += __shfl_xor(p, 1, 64); p += __shfl_xor(p, 2, 64);
      p += __shfl_xor(p, 4, 64); p += __shfl_xor(p, 8, 64);
      if (seg == 0) yout[(size_t)(bg + b)*Ff*OC + (size_t)(i + 1)*OC + o] = s_rb[o] + p;
    }
  }
}

extern "C" void kernel_launch(void* const* d_in, const int* in_sizes, int n_in,
                              void* d_out, int out_size, void* d_ws, size_t ws_size,
                              hipStream_t stream)
{
  (void)in_sizes; (void)n_in; (void)out_size; (void)ws_size;
  const float* y_past = (const float*)d_in[0];
  const float* t_in   = (const float*)d_in[1];
  const float* coeffs = (const float*)d_in[2];
  // d_in[3] = input_length (fixed 256)
  const float* zx_wih = (const float*)d_in[4];
  const float* zx_whh = (const float*)d_in[5];
  const float* zx_b   = (const float*)d_in[6];
  const float* zx_bn  = (const float*)d_in[7];
  const float* zxl_w  = (const float*)d_in[8];
  const float* zxl_b  = (const float*)d_in[9];
  const float* zy_wih = (const float*)d_in[10];
  const float* zy_whh = (const float*)d_in[11];
  const float* zy_b   = (const float*)d_in[12];
  const float* zy_bn  = (const float*)d_in[13];
  const float* fw1 = (const float*)d_in[14];
  const float* fb1 = (const float*)d_in[15];
  const float* fw2 = (const float*)d_in[16];
  const float* fb2 = (const float*)d_in[17];
  const float* fw3 = (const float*)d_in[18];
  const float* fb3 = (const float*)d_in[19];
  const float* r_w = (const float*)d_in[20];
  const float* r_b = (const float*)d_in[21];

  float* ws = (float*)d_ws;
  float* zx_buf = ws;                              // B*T*NZ fp32 = 8.39 MB
  float* zy_buf = ws + (size_t)Bb*Tt*NZ;           // B*H fp32   = 256 KB

  gru_fused_kernel<<<Bb, 768, 0, stream>>>(coeffs, y_past, t_in,
                                           zx_wih, zx_whh, zx_b, zx_bn,
                                           zxl_w, zxl_b,
                                           zy_wih, zy_whh, zy_b, zy_bn,
                                           zx_buf, zy_buf);
  cde_fp32_kernel<<<Bb/BBt, 512, 0, stream>>>(zy_buf, zx_buf, t_in,
                                              fw1, fb1, fw2, fb2, fw3, fb3,
                                              r_w, r_b, (float*)d_out);
}